// Round 6
// baseline (46.099 us; speedup 1.0000x reference)
//
#include <hip/hip_runtime.h>

#define EMB_DIM 64
#define ROWS_PER_BLOCK 16   // 256 threads = 4 waves x (4 groups x 16 lanes)

typedef float v4f __attribute__((ext_vector_type(4)));

__device__ __forceinline__ int lower_bound_i32(const int* __restrict__ arr, int n, int val) {
    int lo = 0, hi = n;
    while (lo < hi) {
        int mid = (lo + hi) >> 1;
        if (arr[mid] < val) lo = mid + 1;
        else hi = mid;
    }
    return lo;
}

// Single dispatch. Each 64-lane wave owns 4 output rows: lanes 0..4 run 5
// parallel binary searches (wave-local, no LDS, no __syncthreads — waves
// never block each other), results broadcast via __shfl. Then 16 lanes per
// row gather with an 8-deep predicated load batch (one HBM round-trip for
// ~93% of rows) and a nontemporal float4 store.
__global__ __launch_bounds__(256) void emb_lookup_mean_wave_kernel(
        const int*   __restrict__ values,
        const int*   __restrict__ rows,
        const float* __restrict__ table,
        float*       __restrict__ out,
        int nnz, int n_rows) {
    int t         = threadIdx.x;
    int wave      = t >> 6;
    int lane64    = t & 63;
    int wave_row0 = blockIdx.x * ROWS_PER_BLOCK + wave * 4;

    // 5 parallel searches over the L2-resident rows[] (2 MB).
    int off_l = 0;
    if (lane64 < 5) off_l = lower_bound_i32(rows, nnz, wave_row0 + lane64);

    int grp  = lane64 >> 4;     // 0..3: which of the wave's 4 rows
    int lane = lane64 & 15;     // 0..15: float4 slot within the row
    int start = __shfl(off_l, grp,     64);
    int end   = __shfl(off_l, grp + 1, 64);
    int row   = wave_row0 + grp;
    if (row >= n_rows) return;

    int cnt = end - start;
    float4 acc = make_float4(0.f, 0.f, 0.f, 0.f);

    for (int j = start; j < end; j += 8) {
        int n = end - j;          // uniform within the 16-lane group

        // Phase 1: up to 8 independent key loads (same addr across group -> broadcast)
        int k0 = 0, k1 = 0, k2 = 0, k3 = 0, k4 = 0, k5 = 0, k6 = 0, k7 = 0;
        k0 = values[j];
        if (n > 1) k1 = values[j + 1];
        if (n > 2) k2 = values[j + 2];
        if (n > 3) k3 = values[j + 3];
        if (n > 4) k4 = values[j + 4];
        if (n > 5) k5 = values[j + 5];
        if (n > 6) k6 = values[j + 6];
        if (n > 7) k7 = values[j + 7];

        // Phase 2: up to 8 independent 256B row loads, all in flight
        float4 z = make_float4(0.f, 0.f, 0.f, 0.f);
        float4 v0 = z, v1 = z, v2 = z, v3 = z, v4 = z, v5 = z, v6 = z, v7 = z;
        v0 = reinterpret_cast<const float4*>(table + (size_t)k0 * EMB_DIM)[lane];
        if (n > 1) v1 = reinterpret_cast<const float4*>(table + (size_t)k1 * EMB_DIM)[lane];
        if (n > 2) v2 = reinterpret_cast<const float4*>(table + (size_t)k2 * EMB_DIM)[lane];
        if (n > 3) v3 = reinterpret_cast<const float4*>(table + (size_t)k3 * EMB_DIM)[lane];
        if (n > 4) v4 = reinterpret_cast<const float4*>(table + (size_t)k4 * EMB_DIM)[lane];
        if (n > 5) v5 = reinterpret_cast<const float4*>(table + (size_t)k5 * EMB_DIM)[lane];
        if (n > 6) v6 = reinterpret_cast<const float4*>(table + (size_t)k6 * EMB_DIM)[lane];
        if (n > 7) v7 = reinterpret_cast<const float4*>(table + (size_t)k7 * EMB_DIM)[lane];

        // Tree sum (masked-off vi are zero)
        float4 s01, s23, s45, s67, sA, sB;
        s01.x = v0.x + v1.x; s01.y = v0.y + v1.y; s01.z = v0.z + v1.z; s01.w = v0.w + v1.w;
        s23.x = v2.x + v3.x; s23.y = v2.y + v3.y; s23.z = v2.z + v3.z; s23.w = v2.w + v3.w;
        s45.x = v4.x + v5.x; s45.y = v4.y + v5.y; s45.z = v4.z + v5.z; s45.w = v4.w + v5.w;
        s67.x = v6.x + v7.x; s67.y = v6.y + v7.y; s67.z = v6.z + v7.z; s67.w = v6.w + v7.w;
        sA.x = s01.x + s23.x; sA.y = s01.y + s23.y; sA.z = s01.z + s23.z; sA.w = s01.w + s23.w;
        sB.x = s45.x + s67.x; sB.y = s45.y + s67.y; sB.z = s45.z + s67.z; sB.w = s45.w + s67.w;
        acc.x += sA.x + sB.x; acc.y += sA.y + sB.y; acc.z += sA.z + sB.z; acc.w += sA.w + sB.w;
    }

    float inv = (cnt > 0) ? (1.0f / (float)cnt) : 0.0f;
    v4f r;
    r.x = acc.x * inv; r.y = acc.y * inv; r.z = acc.z * inv; r.w = acc.w * inv;

    // Nontemporal: out is never re-read; keep L2 for table-row reuse.
    v4f* dst = reinterpret_cast<v4f*>(out + (size_t)row * EMB_DIM) + lane;
    __builtin_nontemporal_store(r, dst);
}

extern "C" void kernel_launch(void* const* d_in, const int* in_sizes, int n_in,
                              void* d_out, int out_size, void* d_ws, size_t ws_size,
                              hipStream_t stream) {
    const int*   values = (const int*)d_in[0];
    const int*   rows   = (const int*)d_in[1];
    const float* table  = (const float*)d_in[2];
    float*       out    = (float*)d_out;

    int nnz    = in_sizes[0];
    int n_rows = out_size / EMB_DIM;   // BATCH * SLOT_NUM = 106496 (multiple of 16)

    int block = 256;
    int grid  = (n_rows + ROWS_PER_BLOCK - 1) / ROWS_PER_BLOCK;

    emb_lookup_mean_wave_kernel<<<grid, block, 0, stream>>>(values, rows, table, out,
                                                            nnz, n_rows);
}

// Round 7
// 35.788 us; speedup vs baseline: 1.2881x; 1.2881x over previous
//
#include <hip/hip_runtime.h>

#define EMB_DIM 64
#define LANES_PER_ROW 16   // 16 lanes x float4 = 64 floats = one embedding row

typedef float v4f __attribute__((ext_vector_type(4)));

// ---------------- Kernel 1: CSR offsets from sorted row_indices ----------------
__global__ __launch_bounds__(256) void build_offsets_kernel(
        const int* __restrict__ rows,
        int*       __restrict__ off,
        int nnz, int n_rows) {
    int j = blockIdx.x * blockDim.x + threadIdx.x;
    if (j >= nnz) return;
    int r  = rows[j];
    int rp = (j == 0) ? -1 : rows[j - 1];
    for (int rr = rp + 1; rr <= r; ++rr) off[rr] = j;
    if (j == nnz - 1) {
        for (int rr = r + 1; rr <= n_rows; ++rr) off[rr] = nnz;
    }
}

// ---------------- Kernel 2: gather + mean, 8-deep predicated batch ----------------
__global__ __launch_bounds__(256) void emb_lookup_mean_kernel(
        const int*   __restrict__ values,
        const int*   __restrict__ off,
        const float* __restrict__ table,
        float*       __restrict__ out,
        int n_rows) {
    int tid  = blockIdx.x * blockDim.x + threadIdx.x;
    int row  = tid >> 4;          // 16 lanes per output row
    int lane = tid & 15;
    if (row >= n_rows) return;

    int start = off[row];         // coalesced: adjacent groups read adjacent ints
    int end   = off[row + 1];
    int cnt   = end - start;

    float4 acc = make_float4(0.f, 0.f, 0.f, 0.f);

    for (int j = start; j < end; j += 8) {
        int n = end - j;          // uniform within the 16-lane group

        // Phase 1: up to 8 independent key loads (same addr across group -> broadcast)
        int k0 = 0, k1 = 0, k2 = 0, k3 = 0, k4 = 0, k5 = 0, k6 = 0, k7 = 0;
        k0 = values[j];
        if (n > 1) k1 = values[j + 1];
        if (n > 2) k2 = values[j + 2];
        if (n > 3) k3 = values[j + 3];
        if (n > 4) k4 = values[j + 4];
        if (n > 5) k5 = values[j + 5];
        if (n > 6) k6 = values[j + 6];
        if (n > 7) k7 = values[j + 7];

        // Phase 2: up to 8 independent 256B row loads, all in flight
        float4 z = make_float4(0.f, 0.f, 0.f, 0.f);
        float4 v0 = z, v1 = z, v2 = z, v3 = z, v4 = z, v5 = z, v6 = z, v7 = z;
        v0 = reinterpret_cast<const float4*>(table + (size_t)k0 * EMB_DIM)[lane];
        if (n > 1) v1 = reinterpret_cast<const float4*>(table + (size_t)k1 * EMB_DIM)[lane];
        if (n > 2) v2 = reinterpret_cast<const float4*>(table + (size_t)k2 * EMB_DIM)[lane];
        if (n > 3) v3 = reinterpret_cast<const float4*>(table + (size_t)k3 * EMB_DIM)[lane];
        if (n > 4) v4 = reinterpret_cast<const float4*>(table + (size_t)k4 * EMB_DIM)[lane];
        if (n > 5) v5 = reinterpret_cast<const float4*>(table + (size_t)k5 * EMB_DIM)[lane];
        if (n > 6) v6 = reinterpret_cast<const float4*>(table + (size_t)k6 * EMB_DIM)[lane];
        if (n > 7) v7 = reinterpret_cast<const float4*>(table + (size_t)k7 * EMB_DIM)[lane];

        // Tree sum (masked-off vi are zero)
        float4 s01, s23, s45, s67, sA, sB;
        s01.x = v0.x + v1.x; s01.y = v0.y + v1.y; s01.z = v0.z + v1.z; s01.w = v0.w + v1.w;
        s23.x = v2.x + v3.x; s23.y = v2.y + v3.y; s23.z = v2.z + v3.z; s23.w = v2.w + v3.w;
        s45.x = v4.x + v5.x; s45.y = v4.y + v5.y; s45.z = v4.z + v5.z; s45.w = v4.w + v5.w;
        s67.x = v6.x + v7.x; s67.y = v6.y + v7.y; s67.z = v6.z + v7.z; s67.w = v6.w + v7.w;
        sA.x = s01.x + s23.x; sA.y = s01.y + s23.y; sA.z = s01.z + s23.z; sA.w = s01.w + s23.w;
        sB.x = s45.x + s67.x; sB.y = s45.y + s67.y; sB.z = s45.z + s67.z; sB.w = s45.w + s67.w;
        acc.x += sA.x + sB.x; acc.y += sA.y + sB.y; acc.z += sA.z + sB.z; acc.w += sA.w + sB.w;
    }

    float inv = (cnt > 0) ? (1.0f / (float)cnt) : 0.0f;
    v4f r;
    r.x = acc.x * inv; r.y = acc.y * inv; r.z = acc.z * inv; r.w = acc.w * inv;

    // Nontemporal: out is write-once; keep L2/L3 capacity for duplicate table rows.
    v4f* dst = reinterpret_cast<v4f*>(out + (size_t)row * EMB_DIM) + lane;
    __builtin_nontemporal_store(r, dst);
}

// ---------------- Fallback (binary search) if d_ws is too small ----------------
__device__ __forceinline__ int lower_bound_i32(const int* __restrict__ arr, int n, int val) {
    int lo = 0, hi = n;
    while (lo < hi) {
        int mid = (lo + hi) >> 1;
        if (arr[mid] < val) lo = mid + 1;
        else hi = mid;
    }
    return lo;
}

__global__ __launch_bounds__(256) void emb_lookup_mean_bsearch_kernel(
        const int*   __restrict__ values,
        const int*   __restrict__ rows,
        const float* __restrict__ table,
        float*       __restrict__ out,
        int nnz, int n_rows) {
    int tid  = blockIdx.x * blockDim.x + threadIdx.x;
    int row  = tid >> 4;
    int lane = tid & 15;
    if (row >= n_rows) return;
    int start = lower_bound_i32(rows, nnz, row);
    int end   = lower_bound_i32(rows, nnz, row + 1);
    float4 acc = make_float4(0.f, 0.f, 0.f, 0.f);
    for (int j = start; j < end; ++j) {
        int key = values[j];
        float4 v = reinterpret_cast<const float4*>(table + (size_t)key * EMB_DIM)[lane];
        acc.x += v.x; acc.y += v.y; acc.z += v.z; acc.w += v.w;
    }
    int   cnt = end - start;
    float inv = (cnt > 0) ? (1.0f / (float)cnt) : 0.0f;
    acc.x *= inv; acc.y *= inv; acc.z *= inv; acc.w *= inv;
    reinterpret_cast<float4*>(out + (size_t)row * EMB_DIM)[lane] = acc;
}

extern "C" void kernel_launch(void* const* d_in, const int* in_sizes, int n_in,
                              void* d_out, int out_size, void* d_ws, size_t ws_size,
                              hipStream_t stream) {
    const int*   values = (const int*)d_in[0];
    const int*   rows   = (const int*)d_in[1];
    const float* table  = (const float*)d_in[2];
    float*       out    = (float*)d_out;

    int nnz    = in_sizes[0];
    int n_rows = out_size / EMB_DIM;   // BATCH * SLOT_NUM = 106496

    int block = 256;
    int grid2 = (n_rows * LANES_PER_ROW + block - 1) / block;

    size_t off_bytes = (size_t)(n_rows + 1) * sizeof(int);
    if (ws_size >= off_bytes) {
        int* off = (int*)d_ws;
        int grid1 = (nnz + block - 1) / block;
        build_offsets_kernel<<<grid1, block, 0, stream>>>(rows, off, nnz, n_rows);
        emb_lookup_mean_kernel<<<grid2, block, 0, stream>>>(values, off, table, out, n_rows);
    } else {
        emb_lookup_mean_bsearch_kernel<<<grid2, block, 0, stream>>>(values, rows, table, out,
                                                                    nnz, n_rows);
    }
}